// Round 20
// baseline (174.494 us; speedup 1.0000x reference)
//
#include <hip/hip_runtime.h>
#include <math.h>

// Problem dims
#define TSTEPS 4
#define BB 8
#define NN 25000
#define LLD 64
#define DIN 129

// ws offsets (floats)
#define OFF_I4    24576    // I4[l][4]
#define OFF_R4    24832    // R4[l][4]
#define OFF_A     25088    // A[d][65]
#define OFF_WQ0   33473    // wq0[129]
#define OFF_CA    33602    // cA[65]
#define OFF_C0Q   33667    // c0q
#define OFF_WVO   33668    // wvo[129]
#define OFF_C0    33797    // c0
#define OFF_WQC   33856    // wqc[8][132]
#define OFF_BFRAG 36864    // B-fragments: 2 planes x 32768 ushorts
#define OFF_MEMA  73728    // mem[25000][64] (n-major)
#define OFF_MEMB  1673728  // mem[25000][64]
#define OFF_RLAST 3273728  // r_last[25000]
#define OFF_PART  3298728  // partials [8][98][132]
#define NBLK 98
#define PSTRIDE 132

typedef short s16x8 __attribute__((ext_vector_type(8)));
typedef float f32x4 __attribute__((ext_vector_type(4)));

__device__ __forceinline__ float sigm(float x) { return 1.f / (1.f + __expf(-x)); }
__device__ __forceinline__ float tanh_fast(float x) {
  float ax = fabsf(x);
  float e = __expf(-2.f * ax);
  float t = (1.f - e) / (1.f + e);
  return copysignf(t, x);
}
__device__ __forceinline__ float wred_max(float v) {
#pragma unroll
  for (int m = 32; m; m >>= 1) v = fmaxf(v, __shfl_xor(v, m));
  return v;
}
__device__ __forceinline__ float wred_sum(float v) {
#pragma unroll
  for (int m = 32; m; m >>= 1) v += __shfl_xor(v, m);
  return v;
}
__device__ __forceinline__ unsigned short bf16_rne(float v) {
  unsigned int u = __float_as_uint(v);
  unsigned int r = (u + 0x7FFFu + ((u >> 16) & 1u)) >> 16;
  return (unsigned short)r;
}
__device__ __forceinline__ float bf16_to_f(unsigned short b) {
  return __uint_as_float(((unsigned int)b) << 16);
}

// ---------------- setup (merged): folds + inline-W6 pack ----------------
// block 0: u -> wq0/c0q. blocks 1..9: small folds. blocks 10..41: B-fragment pack
// computing the folded weight inline (no W6 intermediate, no pack dispatch).
__global__ __launch_bounds__(1024) void k_setup(
    const float* __restrict__ W_msg, const float* __restrict__ Wi,
    const float* __restrict__ bi, const float* __restrict__ b_msg,
    const float* __restrict__ bh, const float* __restrict__ Wh,
    const float* __restrict__ Wq, const float* __restrict__ bq,
    const float* __restrict__ Wk, const float* __restrict__ bk,
    const float* __restrict__ Wv, const float* __restrict__ bv,
    const float* __restrict__ W_out, const float* __restrict__ b_out,
    const float* __restrict__ b_t, float* __restrict__ ws) {
  int tid = threadIdx.x;
  if (blockIdx.x == 0) {
    __shared__ float u_lds[64];
    if (tid < 64) {
      float acc = bq[tid];
      for (int l = 0; l < 64; l++) acc += __cosf(b_t[l]) * Wq[(65 + l) * 64 + tid];
      u_lds[tid] = acc;
    }
    __syncthreads();
    if (tid < 129) {
      float acc = 0.f;
      for (int j = 0; j < 64; j++) acc += Wk[tid * 64 + j] * u_lds[j];
      ws[OFF_WQ0 + tid] = acc;
    } else if (tid == 129) {
      float acc = 0.f;
      for (int j = 0; j < 64; j++) acc += bk[j] * u_lds[j];
      ws[OFF_C0Q] = acc;
    }
    return;
  }
  if (blockIdx.x < 10) {                     // small folds
    int id = (blockIdx.x - 1) * 1024 + tid;  // 0..9215
    if (id < 256) {                          // I4[l][g]
      int l = id / 4, g = id % 4;
      float v;
      if (g == 3) v = bh[128 + l];
      else {
        int j = g * 64 + l;
        float bcf = bi[j];
        for (int m = 0; m < 64; m++) bcf += b_msg[m] * Wi[m * 192 + j];
        v = (g < 2) ? (bcf + bh[j]) : bcf;
      }
      ws[OFF_I4 + id] = v;
    } else if (id < 512) {                   // R4[l][g]
      int id2 = id - 256, l = id2 / 4, g = id2 % 4;
      float v = 0.f;
      if (g < 3) {
        for (int m = 0; m < 64; m++) v += W_msg[m] * Wi[m * 192 + g * 64 + l];
      }
      ws[OFF_R4 + id2] = v;
    } else if (id < 8897) {                  // A[d][i]
      int id3 = id - 512, d = id3 / 65, i = id3 % 65;
      float acc = 0.f;
      for (int j = 0; j < 64; j++) acc += Wk[d * 64 + j] * Wq[i * 64 + j];
      ws[OFF_A + id3] = acc;
    } else if (id < 8962) {                  // cA[i]
      int i = id - 8897;
      float acc = 0.f;
      for (int j = 0; j < 64; j++) acc += bk[j] * Wq[i * 64 + j];
      ws[OFF_CA + i] = acc;
    } else if (id < 9091) {                  // wvo[d]
      int d = id - 8962;
      float acc = 0.f;
      for (int j = 0; j < 64; j++) acc += Wv[d * 64 + j] * W_out[j];
      ws[OFF_WVO + d] = acc;
    } else if (id == 9091) {                 // c0
      float acc = b_out[0];
      for (int j = 0; j < 64; j++) acc += bv[j] * W_out[j];
      ws[OFF_C0] = acc;
    }
    return;
  }
  // pack blocks: compute folded weight inline, store bf16 hi/lo fragments
  int id = (blockIdx.x - 10) * 1024 + tid;   // 0..32767
  int r = id & 7, lane = (id >> 3) & 63, kt = (id >> 9) & 3, ct = id >> 11;
  int col = 16 * ct + (lane & 15);
  int k = 32 * kt + ((lane >> 4) << 3) + r;
  int a = col >> 6, l = col & 63;
  float w = 0.f;
  if (k < 64) {
    if (a < 3) {
      for (int m = 0; m < 64; m++) w += W_msg[(k + 1) * 64 + m] * Wi[m * 192 + a * 64 + l];
    }
  } else {
    int k2 = k - 64;
    if (a == 0) w = Wh[k2 * 192 + l];
    else if (a == 1) w = Wh[k2 * 192 + 64 + l];
    else if (a == 3) w = Wh[k2 * 192 + 128 + l];
  }
  unsigned short hb = bf16_rne(w);
  unsigned short lb = bf16_rne(w - bf16_to_f(hb));
  unsigned short* BFu = (unsigned short*)(ws + OFF_BFRAG);
  int idx = ((ct * 4 + kt) * 64 + lane) * 8 + r;
  BFu[idx] = hb;
  BFu[32768 + idx] = lb;
}

// ---------------- device helper: logit merge reduction for batch b ----------------
__device__ __forceinline__ float merge_logit(
    const float* __restrict__ pb, const float* __restrict__ wvo,
    float c0v, float* __restrict__ red, float* __restrict__ fac, int tid) {
  red[tid] = (tid < NBLK) ? pb[tid * PSTRIDE + 129] : -1e30f;
  __syncthreads();
  for (int s = 128; s > 0; s >>= 1) {
    if (tid < s) red[tid] = fmaxf(red[tid], red[tid + s]);
    __syncthreads();
  }
  float mb = red[0];
  __syncthreads();
  if (tid < NBLK) fac[tid] = __expf(pb[tid * PSTRIDE + 129] - mb);
  __syncthreads();
  red[tid] = (tid < NBLK) ? pb[tid * PSTRIDE + 130] * fac[tid] : 0.f;
  __syncthreads();
  for (int s = 128; s > 0; s >>= 1) {
    if (tid < s) red[tid] += red[tid + s];
    __syncthreads();
  }
  float Sb = red[0];
  __syncthreads();
  float acc = 0.f;
  if (tid < DIN) {
    float a0 = 0.f, a1 = 0.f, a2 = 0.f, a3 = 0.f;
    int j = 0;
    for (; j + 3 < NBLK; j += 4) {
      a0 += fac[j] * pb[j * PSTRIDE + tid];
      a1 += fac[j + 1] * pb[(j + 1) * PSTRIDE + tid];
      a2 += fac[j + 2] * pb[(j + 2) * PSTRIDE + tid];
      a3 += fac[j + 3] * pb[(j + 3) * PSTRIDE + tid];
    }
    for (; j < NBLK; j++) a0 += fac[j] * pb[j * PSTRIDE + tid];
    acc = ((a0 + a1) + (a2 + a3)) * wvo[tid];
  }
  red[tid] = (tid < DIN) ? acc : 0.f;
  __syncthreads();
  for (int s = 128; s > 0; s >>= 1) {
    if (tid < s) red[tid] += red[tid + s];
    __syncthreads();
  }
  float lg = red[0] / Sb + c0v;
  __syncthreads();
  return lg;
}

// ---------------- GRU + fused prev-step merge prologue + fused wq tail ----------------
__global__ __launch_bounds__(256, 2) void k_gru(
    const float* __restrict__ t_in, const float* __restrict__ raw,
    float* __restrict__ r_last, const float* __restrict__ w_t,
    const float* __restrict__ b_t, const float* __restrict__ i4p,
    const float* __restrict__ r4p, const unsigned short* __restrict__ BF,
    const float* __restrict__ memPrev, float* __restrict__ memNext,
    const int* __restrict__ tar, const float* __restrict__ A,
    const float* __restrict__ wq0, const float* __restrict__ cA,
    const float* __restrict__ c0q, float* __restrict__ wqc,
    const float* __restrict__ part, const float* __restrict__ wvo,
    const float* __restrict__ c0p, const float* __restrict__ r_label,
    float* __restrict__ out, int tt) {
  __shared__ unsigned short XhiS[64 * 136];
  __shared__ unsigned short XloS[64 * 136];
  __shared__ float tb_lds[64], rn_lds[64];
  __shared__ float q_lds[64];
  __shared__ float mred[256], mfac[NBLK];
  int tid = threadIdx.x;
  int lane = tid & 63;
  int wv = tid >> 6;
  int nbase = blockIdx.x * 64;

  // ---- prologue (tt>0): finalize r_state[tt-1] for my chunk + owned logits ----
  if (tt > 0) {
    int ptt = tt - 1;
    if (tid < 64) {
      int n2 = nbase + tid;
      if (n2 < NN) {
        bool istar = false;
#pragma unroll
        for (int b = 0; b < BB; b++) istar |= (tar[ptt * BB + b] == n2);
        if (!istar) {
          float base = (ptt == 0) ? raw[(BB - 1) * NN + n2] : r_last[n2];
          r_last[n2] = 0.5f * (base + r_label[(ptt * BB + BB - 1) * NN + n2]);
        }
      }
    }
    __syncthreads();
    for (int b = 0; b < BB; b++) {
      int tn = tar[ptt * BB + b];                  // block-uniform
      if ((tn >> 6) != (int)blockIdx.x) continue;  // uniform branch
      float lg = merge_logit(part + b * NBLK * PSTRIDE, wvo, c0p[0], mred, mfac, tid);
      if (tid == 0) {
        out[ptt * BB + b] = lg;
        r_last[tn] = 0.5f * (lg + r_label[(ptt * BB + BB - 1) * NN + tn]);  // ascending b = last wins
      }
      __syncthreads();
    }
    __syncthreads();
  }

  if (tid < 64) {
    int nc = min(nbase + tid, NN - 1);
    tb_lds[tid] = t_in[(tt * BB + BB - 1) * NN + nc];
    rn_lds[tid] = (tt == 0) ? raw[(BB - 1) * NN + nc] : r_last[nc];
  }
  __syncthreads();

  {
    int nl = lane;
    int nc = min(nbase + nl, NN - 1);
    float tb = tb_lds[nl];
    int swz = (nl & 7) << 3;
    const float4* mp4 = (const float4*)(memPrev + (size_t)nc * 64);
#pragma unroll
    for (int c = 0; c < 4; c++) {
      int kc = wv * 32 + c * 8;   // wave-uniform
      float vv[8];
      if (kc < 64) {
#pragma unroll
        for (int j = 0; j < 8; j++) vv[j] = __cosf(tb * w_t[kc + j] + b_t[kc + j]);
      } else if (tt == 0) {
#pragma unroll
        for (int j = 0; j < 8; j++) vv[j] = 0.f;
      } else {
        int d0 = kc - 64;
        float4 f0 = mp4[d0 >> 2];
        float4 f1 = mp4[(d0 >> 2) + 1];
        vv[0] = f0.x; vv[1] = f0.y; vv[2] = f0.z; vv[3] = f0.w;
        vv[4] = f1.x; vv[5] = f1.y; vv[6] = f1.z; vv[7] = f1.w;
      }
      s16x8 h8, l8;
#pragma unroll
      for (int j = 0; j < 8; j++) {
        unsigned short hb = bf16_rne(vv[j]);
        h8[j] = (short)hb;
        l8[j] = (short)bf16_rne(vv[j] - bf16_to_f(hb));
      }
      int off = nl * 136 + (kc ^ swz);
      *(s16x8*)(XhiS + off) = h8;
      *(s16x8*)(XloS + off) = l8;
    }
  }
  __syncthreads();

  const s16x8* BF8 = (const s16x8*)BF;
  f32x4 acc[4][4];
#pragma unroll
  for (int g = 0; g < 4; g++)
#pragma unroll
    for (int m = 0; m < 4; m++) acc[g][m] = (f32x4){0.f, 0.f, 0.f, 0.f};

  int swzA = (lane & 7) << 3;
#pragma unroll
  for (int kt = 0; kt < 4; kt++) {
    s16x8 bh[4], bl[4];
#pragma unroll
    for (int g = 0; g < 4; g++) {
      int ct = wv + 4 * g;
      bh[g] = BF8[(ct * 4 + kt) * 64 + lane];
      bl[g] = BF8[4096 + (ct * 4 + kt) * 64 + lane];
    }
#pragma unroll
    for (int m = 0; m < 4; m++) {
      int row = 16 * m + (lane & 15);
      int off = row * 136 + ((32 * kt + 8 * (lane >> 4)) ^ swzA);
      s16x8 ah = *(const s16x8*)(XhiS + off);
      s16x8 al = *(const s16x8*)(XloS + off);
#pragma unroll
      for (int g = 0; g < 4; g++) {
        acc[g][m] = __builtin_amdgcn_mfma_f32_16x16x32_bf16(ah, bh[g], acc[g][m], 0, 0, 0);
        acc[g][m] = __builtin_amdgcn_mfma_f32_16x16x32_bf16(ah, bl[g], acc[g][m], 0, 0, 0);
        acc[g][m] = __builtin_amdgcn_mfma_f32_16x16x32_bf16(al, bh[g], acc[g][m], 0, 0, 0);
      }
    }
  }

  int myl = 16 * wv + (lane & 15);
  float4 iv = ((const float4*)i4p)[myl];
  float4 rv = ((const float4*)r4p)[myl];
  int kmem = 64 + myl;
  int slot = kmem & ~7;
  int wel = kmem & 7;
#pragma unroll
  for (int m = 0; m < 4; m++) {
#pragma unroll
    for (int i = 0; i < 4; i++) {
      int nloc = 16 * m + (lane >> 4) * 4 + i;
      float rn = rn_lds[nloc];
      float gRv = acc[0][m][i] + iv.x + rn * rv.x;
      float gZv = acc[1][m][i] + iv.y + rn * rv.y;
      float aNv = acc[2][m][i] + iv.z + rn * rv.z;
      float hNv = acc[3][m][i] + iv.w;
      float rg = sigm(gRv);
      float zg = sigm(gZv);
      float ng = tanh_fast(aNv + rg * hNv);
      int offm = nloc * 136 + (slot ^ ((nloc & 7) << 3)) + wel;
      float mp = bf16_to_f(XhiS[offm]) + bf16_to_f(XloS[offm]);
      int n = nbase + nloc;
      if (n < NN) memNext[(size_t)n * 64 + myl] = (1.f - zg) * ng + zg * mp;
    }
  }

  // ---- fused wq tail: block owning tar_b's row computes wqc[b] ----
  for (int b = 0; b < BB; b++) {
    int tn = tar[tt * BB + b];                  // block-uniform
    if ((tn >> 6) != (int)blockIdx.x) continue; // uniform branch
    __syncthreads();                            // memNext row fully written & visible
    if (tid < 64) q_lds[tid] = memNext[(size_t)tn * 64 + tid];
    __syncthreads();
    float tr = (tt == 0) ? raw[b * NN + tn] : r_last[tn];
    if (tid < 129) {
      const float* Ar = A + tid * 65;
      float acc2 = wq0[tid] + tr * Ar[0];
#pragma unroll 8
      for (int k = 0; k < 64; k++) acc2 += q_lds[k] * Ar[1 + k];
      wqc[b * 132 + tid] = acc2;
    } else if (tid == 129) {
      float acc2 = c0q[0] + tr * cA[0];
      for (int k = 0; k < 64; k++) acc2 += q_lds[k] * cA[1 + k];
      wqc[b * 132 + 129] = acc2;
    }
    __syncthreads();
  }
}

// ---------------- attention: shuffle-based phase-2 (3 barriers, no e/t LDS) ----------
__global__ __launch_bounds__(256) void k_attn(
    const float* __restrict__ t_in, const float* __restrict__ raw,
    const float* __restrict__ r_last, const int* __restrict__ n_mask,
    const float* __restrict__ w_t, const float* __restrict__ b_t,
    const float* __restrict__ wqc, const float* __restrict__ mem2,
    float* __restrict__ part, int tt) {
  __shared__ float wq_lds[132];
  __shared__ float red4[4], redS[4], redR[4];
  __shared__ float pmw[4][64], pew[4][64];

  int tid = threadIdx.x;
  int lane = tid & 63;
  int wvid = tid >> 6;
  int b = blockIdx.y;
  int n0 = blockIdx.x * 256;
  int n = n0 + tid;
  int nc = min(n, NN - 1);
  bool valid = (n < NN);

  if (tid < 130) wq_lds[tid] = wqc[b * 132 + tid];

  float tb = t_in[(tt * BB + b) * NN + nc];
  int mk = n_mask[(tt * BB + b) * NN + nc];
  float rn = (tt == 0) ? raw[b * NN + nc] : r_last[nc];
  __syncthreads();

  // score: 16 x float4 contiguous loads of mem2 row nc
  float sc = rn * wq_lds[0];
  const float4* m4 = (const float4*)(mem2 + (size_t)nc * 64);
#pragma unroll
  for (int q = 0; q < 16; q++) {
    float4 v = m4[q];
    sc += v.x * wq_lds[1 + 4 * q] + v.y * wq_lds[2 + 4 * q] +
          v.z * wq_lds[3 + 4 * q] + v.w * wq_lds[4 + 4 * q];
  }
#pragma unroll 8
  for (int l = 0; l < 64; l++) sc += __cosf(tb * w_t[l] + b_t[l]) * wq_lds[65 + l];
  float score = (sc + wq_lds[129]) * 0.125f;
  bool act = valid && (mk > 0);

  float mw = wred_max(act ? score : -1e30f);
  if (lane == 0) red4[wvid] = mw;
  __syncthreads();
  float mb = fmaxf(fmaxf(red4[0], red4[1]), fmaxf(red4[2], red4[3]));

  float e = act ? __expf(score - mb) : 0.f;
  float sw = wred_sum(e);
  float sr = wred_sum(e * rn);
  if (lane == 0) { redS[wvid] = sw; redR[wvid] = sr; }

  // phase 2: wave-local, via shuffles (wave w's e/tb cover exactly rows n0+64w..+63)
  {
    int rbase = n0 + wvid * 64;
    float a0 = 0.f, a1 = 0.f, a2 = 0.f, a3 = 0.f;
    float a4 = 0.f, a5 = 0.f, a6 = 0.f, a7 = 0.f;
#pragma unroll 2
    for (int i = 0; i < 64; i += 8) {
      a0 += __shfl(e, i + 0) * mem2[(size_t)min(rbase + i + 0, NN - 1) * 64 + lane];
      a1 += __shfl(e, i + 1) * mem2[(size_t)min(rbase + i + 1, NN - 1) * 64 + lane];
      a2 += __shfl(e, i + 2) * mem2[(size_t)min(rbase + i + 2, NN - 1) * 64 + lane];
      a3 += __shfl(e, i + 3) * mem2[(size_t)min(rbase + i + 3, NN - 1) * 64 + lane];
      a4 += __shfl(e, i + 4) * mem2[(size_t)min(rbase + i + 4, NN - 1) * 64 + lane];
      a5 += __shfl(e, i + 5) * mem2[(size_t)min(rbase + i + 5, NN - 1) * 64 + lane];
      a6 += __shfl(e, i + 6) * mem2[(size_t)min(rbase + i + 6, NN - 1) * 64 + lane];
      a7 += __shfl(e, i + 7) * mem2[(size_t)min(rbase + i + 7, NN - 1) * 64 + lane];
    }
    pmw[wvid][lane] = ((a0 + a1) + (a2 + a3)) + ((a4 + a5) + (a6 + a7));
    float wl = w_t[lane], bl = b_t[lane];
    float peA = 0.f;
#pragma unroll 4
    for (int i = 0; i < 64; i++)
      peA += __shfl(e, i) * __cosf(__shfl(tb, i) * wl + bl);
    pew[wvid][lane] = peA;
  }
  __syncthreads();   // covers redS/redR and pmw/pew

  float Sb = redS[0] + redS[1] + redS[2] + redS[3];
  float Rb = redR[0] + redR[1] + redR[2] + redR[3];

  int pbase = (b * NBLK + blockIdx.x) * PSTRIDE;
  if (tid < 64) part[pbase + 1 + tid] = (pmw[0][tid] + pmw[1][tid]) + (pmw[2][tid] + pmw[3][tid]);
  else if (tid < 128) {
    int d = tid - 64;
    part[pbase + 65 + d] = (pew[0][d] + pew[1][d]) + (pew[2][d] + pew[3][d]);
  }
  else if (tid == 128) part[pbase + 0] = Rb;
  else if (tid == 129) part[pbase + 129] = mb;
  else if (tid == 130) part[pbase + 130] = Sb;
}

// ---------------- final logits for the last step (8 blocks) ----------------
__global__ __launch_bounds__(256) void k_fin(
    const float* __restrict__ part, const float* __restrict__ wvo,
    const float* __restrict__ c0p, float* __restrict__ out, int tt) {
  __shared__ float red[256], fac[NBLK];
  int tid = threadIdx.x;
  int b = blockIdx.x;
  float lg = merge_logit(part + b * NBLK * PSTRIDE, wvo, c0p[0], red, fac, tid);
  if (tid == 0) out[tt * BB + b] = lg;
}

extern "C" void kernel_launch(void* const* d_in, const int* in_sizes, int n_in,
                              void* d_out, int out_size, void* d_ws, size_t ws_size,
                              hipStream_t stream) {
  const float* raw     = (const float*)d_in[0];
  const float* r_label = (const float*)d_in[1];
  const float* t_in    = (const float*)d_in[2];
  const int*   tar     = (const int*)d_in[4];
  const int*   n_mask  = (const int*)d_in[5];
  const float* w_t     = (const float*)d_in[6];
  const float* b_t     = (const float*)d_in[7];
  const float* W_msg   = (const float*)d_in[8];
  const float* b_msg   = (const float*)d_in[9];
  const float* Wi      = (const float*)d_in[10];
  const float* Wh      = (const float*)d_in[11];
  const float* bi      = (const float*)d_in[12];
  const float* bh      = (const float*)d_in[13];
  const float* Wq      = (const float*)d_in[14];
  const float* bq      = (const float*)d_in[15];
  const float* Wk      = (const float*)d_in[16];
  const float* bk      = (const float*)d_in[17];
  const float* Wv      = (const float*)d_in[18];
  const float* bv      = (const float*)d_in[19];
  const float* W_out   = (const float*)d_in[20];
  const float* b_out   = (const float*)d_in[21];

  float* ws  = (float*)d_ws;
  float* out = (float*)d_out;

  k_setup<<<42, 1024, 0, stream>>>(W_msg, Wi, bi, b_msg, bh, Wh, Wq, bq, Wk, bk,
                                   Wv, bv, W_out, b_out, b_t, ws);

  for (int tt = 0; tt < TSTEPS; tt++) {
    float* mp = ws + ((tt & 1) ? OFF_MEMB : OFF_MEMA);
    float* mn = ws + ((tt & 1) ? OFF_MEMA : OFF_MEMB);
    k_gru<<<dim3((NN + 63) / 64), dim3(256), 0, stream>>>(
        t_in, raw, ws + OFF_RLAST, w_t, b_t,
        ws + OFF_I4, ws + OFF_R4, (const unsigned short*)(ws + OFF_BFRAG),
        mp, mn, tar, ws + OFF_A, ws + OFF_WQ0, ws + OFF_CA, ws + OFF_C0Q,
        ws + OFF_WQC, ws + OFF_PART, ws + OFF_WVO, ws + OFF_C0,
        r_label, out, tt);
    k_attn<<<dim3(NBLK, BB), dim3(256), 0, stream>>>(
        t_in, raw, ws + OFF_RLAST, n_mask, w_t, b_t,
        ws + OFF_WQC, mn, ws + OFF_PART, tt);
  }
  k_fin<<<dim3(BB), dim3(256), 0, stream>>>(
      ws + OFF_PART, ws + OFF_WVO, ws + OFF_C0, out, TSTEPS - 1);
}

// Round 21
// 170.780 us; speedup vs baseline: 1.0217x; 1.0217x over previous
//
#include <hip/hip_runtime.h>
#include <math.h>

// Problem dims
#define TSTEPS 4
#define BB 8
#define NN 25000
#define LLD 64
#define DIN 129

// ws offsets (floats)
#define OFF_W6    0        // W6[k][l][6]
#define OFF_I4    24576    // I4[l][4]
#define OFF_R4    24832    // R4[l][4]
#define OFF_A     25088    // A[d][65]
#define OFF_WQ0   33473    // wq0[129]
#define OFF_CA    33602    // cA[65]
#define OFF_C0Q   33667    // c0q
#define OFF_WVO   33668    // wvo[129]
#define OFF_C0    33797    // c0
#define OFF_WQC   33856    // wqc[8][132]
#define OFF_BFRAG 36864    // B-fragments: 2 planes x 32768 ushorts
#define OFF_MEMA  73728    // mem[25000][64] (n-major)
#define OFF_MEMB  1673728  // mem[25000][64]
#define OFF_RLAST 3273728  // r_last[25000]
#define OFF_PART  3298728  // partials [8][98][132]
#define NBLK 98
#define PSTRIDE 132

typedef short s16x8 __attribute__((ext_vector_type(8)));
typedef float f32x4 __attribute__((ext_vector_type(4)));

__device__ __forceinline__ float sigm(float x) { return 1.f / (1.f + __expf(-x)); }
__device__ __forceinline__ float tanh_fast(float x) {
  float ax = fabsf(x);
  float e = __expf(-2.f * ax);
  float t = (1.f - e) / (1.f + e);
  return copysignf(t, x);
}
__device__ __forceinline__ float wred_max(float v) {
#pragma unroll
  for (int m = 32; m; m >>= 1) v = fmaxf(v, __shfl_xor(v, m));
  return v;
}
__device__ __forceinline__ float wred_sum(float v) {
#pragma unroll
  for (int m = 32; m; m >>= 1) v += __shfl_xor(v, m);
  return v;
}
__device__ __forceinline__ unsigned short bf16_rne(float v) {
  unsigned int u = __float_as_uint(v);
  unsigned int r = (u + 0x7FFFu + ((u >> 16) & 1u)) >> 16;
  return (unsigned short)r;
}
__device__ __forceinline__ float bf16_to_f(unsigned short b) {
  return __uint_as_float(((unsigned int)b) << 16);
}

// ---------------- setup: fold weights (block 0 computes u -> wq0/c0q) ----------------
__global__ __launch_bounds__(1024) void k_setup(
    const float* __restrict__ W_msg, const float* __restrict__ Wi,
    const float* __restrict__ bi, const float* __restrict__ b_msg,
    const float* __restrict__ bh, const float* __restrict__ Wh,
    const float* __restrict__ Wq, const float* __restrict__ bq,
    const float* __restrict__ Wk, const float* __restrict__ bk,
    const float* __restrict__ Wv, const float* __restrict__ bv,
    const float* __restrict__ W_out, const float* __restrict__ b_out,
    const float* __restrict__ b_t, float* __restrict__ ws) {
  if (blockIdx.x == 0) {
    __shared__ float u_lds[64];
    int tid = threadIdx.x;
    if (tid < 64) {
      float acc = bq[tid];
      for (int l = 0; l < 64; l++) acc += __cosf(b_t[l]) * Wq[(65 + l) * 64 + tid];
      u_lds[tid] = acc;
    }
    __syncthreads();
    if (tid < 129) {
      float acc = 0.f;
      for (int j = 0; j < 64; j++) acc += Wk[tid * 64 + j] * u_lds[j];
      ws[OFF_WQ0 + tid] = acc;
    } else if (tid == 129) {
      float acc = 0.f;
      for (int j = 0; j < 64; j++) acc += bk[j] * u_lds[j];
      ws[OFF_C0Q] = acc;
    }
    return;
  }
  int id = (blockIdx.x - 1) * 1024 + threadIdx.x;
  if (id < 24576) {                        // W6[k][l][g]
    int k = id / 384, rem = id % 384, l = rem / 6, g = rem % 6;
    float acc = 0.f;
    if (g < 3) {
      for (int m = 0; m < 64; m++) acc += W_msg[(k + 1) * 64 + m] * Wi[m * 192 + g * 64 + l];
    } else {
      acc = Wh[k * 192 + (g - 3) * 64 + l];
    }
    ws[OFF_W6 + id] = acc;
  } else if (id < 24832) {                 // I4[l][g]
    int id2 = id - 24576, l = id2 / 4, g = id2 % 4;
    float v;
    if (g == 3) v = bh[128 + l];
    else {
      int j = g * 64 + l;
      float bcf = bi[j];
      for (int m = 0; m < 64; m++) bcf += b_msg[m] * Wi[m * 192 + j];
      v = (g < 2) ? (bcf + bh[j]) : bcf;
    }
    ws[OFF_I4 + id2] = v;
  } else if (id < 25088) {                 // R4[l][g]
    int id2 = id - 24832, l = id2 / 4, g = id2 % 4;
    float v = 0.f;
    if (g < 3) {
      for (int m = 0; m < 64; m++) v += W_msg[m] * Wi[m * 192 + g * 64 + l];
    }
    ws[OFF_R4 + id2] = v;
  } else if (id < 33473) {                 // A[d][i]
    int id3 = id - 25088, d = id3 / 65, i = id3 % 65;
    float acc = 0.f;
    for (int j = 0; j < 64; j++) acc += Wk[d * 64 + j] * Wq[i * 64 + j];
    ws[OFF_A + id3] = acc;
  } else if (id < 33538) {                 // cA[i]
    int i = id - 33473;
    float acc = 0.f;
    for (int j = 0; j < 64; j++) acc += bk[j] * Wq[i * 64 + j];
    ws[OFF_CA + i] = acc;
  } else if (id < 33667) {                 // wvo[d]
    int d = id - 33538;
    float acc = 0.f;
    for (int j = 0; j < 64; j++) acc += Wv[d * 64 + j] * W_out[j];
    ws[OFF_WVO + d] = acc;
  } else if (id == 33667) {                // c0
    float acc = b_out[0];
    for (int j = 0; j < 64; j++) acc += bv[j] * W_out[j];
    ws[OFF_C0] = acc;
  }
}

// ---------------- pack W into MFMA B-fragment order (hi/lo bf16 planes) ----------------
__global__ __launch_bounds__(1024) void k_pack(
    const float* __restrict__ ws_r, float* __restrict__ ws) {
  int id = blockIdx.x * 1024 + threadIdx.x;   // 32768 items
  int r = id & 7, lane = (id >> 3) & 63, kt = (id >> 9) & 3, ct = id >> 11;
  int col = 16 * ct + (lane & 15);
  int k = 32 * kt + ((lane >> 4) << 3) + r;
  int a = col >> 6, l = col & 63;
  float w = 0.f;
  if (k < 64) {
    if (a < 3) w = ws_r[OFF_W6 + (k * 64 + l) * 6 + a];
  } else {
    int k2 = k - 64;
    if (a == 0) w = ws_r[OFF_W6 + (k2 * 64 + l) * 6 + 3];
    else if (a == 1) w = ws_r[OFF_W6 + (k2 * 64 + l) * 6 + 4];
    else if (a == 3) w = ws_r[OFF_W6 + (k2 * 64 + l) * 6 + 5];
  }
  unsigned short hb = bf16_rne(w);
  unsigned short lb = bf16_rne(w - bf16_to_f(hb));
  unsigned short* BFu = (unsigned short*)(ws + OFF_BFRAG);
  int idx = ((ct * 4 + kt) * 64 + lane) * 8 + r;
  BFu[idx] = hb;
  BFu[32768 + idx] = lb;
}

// ---------------- device helper: logit merge reduction for batch b ----------------
__device__ __forceinline__ float merge_logit(
    const float* __restrict__ pb, const float* __restrict__ wvo,
    float c0v, float* __restrict__ red, float* __restrict__ fac, int tid) {
  red[tid] = (tid < NBLK) ? pb[tid * PSTRIDE + 129] : -1e30f;
  __syncthreads();
  for (int s = 128; s > 0; s >>= 1) {
    if (tid < s) red[tid] = fmaxf(red[tid], red[tid + s]);
    __syncthreads();
  }
  float mb = red[0];
  __syncthreads();
  if (tid < NBLK) fac[tid] = __expf(pb[tid * PSTRIDE + 129] - mb);
  __syncthreads();
  red[tid] = (tid < NBLK) ? pb[tid * PSTRIDE + 130] * fac[tid] : 0.f;
  __syncthreads();
  for (int s = 128; s > 0; s >>= 1) {
    if (tid < s) red[tid] += red[tid + s];
    __syncthreads();
  }
  float Sb = red[0];
  __syncthreads();
  float acc = 0.f;
  if (tid < DIN) {
    float a0 = 0.f, a1 = 0.f, a2 = 0.f, a3 = 0.f;
    int j = 0;
    for (; j + 3 < NBLK; j += 4) {
      a0 += fac[j] * pb[j * PSTRIDE + tid];
      a1 += fac[j + 1] * pb[(j + 1) * PSTRIDE + tid];
      a2 += fac[j + 2] * pb[(j + 2) * PSTRIDE + tid];
      a3 += fac[j + 3] * pb[(j + 3) * PSTRIDE + tid];
    }
    for (; j < NBLK; j++) a0 += fac[j] * pb[j * PSTRIDE + tid];
    acc = ((a0 + a1) + (a2 + a3)) * wvo[tid];
  }
  red[tid] = (tid < DIN) ? acc : 0.f;
  __syncthreads();
  for (int s = 128; s > 0; s >>= 1) {
    if (tid < s) red[tid] += red[tid + s];
    __syncthreads();
  }
  float lg = red[0] / Sb + c0v;
  __syncthreads();
  return lg;
}

// ---------------- GRU + fused prev-step merge prologue + fused wq tail ----------------
__global__ __launch_bounds__(256, 2) void k_gru(
    const float* __restrict__ t_in, const float* __restrict__ raw,
    float* __restrict__ r_last, const float* __restrict__ w_t,
    const float* __restrict__ b_t, const float* __restrict__ i4p,
    const float* __restrict__ r4p, const unsigned short* __restrict__ BF,
    const float* __restrict__ memPrev, float* __restrict__ memNext,
    const int* __restrict__ tar, const float* __restrict__ A,
    const float* __restrict__ wq0, const float* __restrict__ cA,
    const float* __restrict__ c0q, float* __restrict__ wqc,
    const float* __restrict__ part, const float* __restrict__ wvo,
    const float* __restrict__ c0p, const float* __restrict__ r_label,
    float* __restrict__ out, int tt) {
  __shared__ unsigned short XhiS[64 * 136];
  __shared__ unsigned short XloS[64 * 136];
  __shared__ float tb_lds[64], rn_lds[64];
  __shared__ float q_lds[64];
  __shared__ float mred[256], mfac[NBLK];
  int tid = threadIdx.x;
  int lane = tid & 63;
  int wv = tid >> 6;
  int nbase = blockIdx.x * 64;

  // ---- prologue (tt>0): finalize r_state[tt-1] for my chunk + owned logits ----
  if (tt > 0) {
    int ptt = tt - 1;
    if (tid < 64) {
      int n2 = nbase + tid;
      if (n2 < NN) {
        bool istar = false;
#pragma unroll
        for (int b = 0; b < BB; b++) istar |= (tar[ptt * BB + b] == n2);
        if (!istar) {
          float base = (ptt == 0) ? raw[(BB - 1) * NN + n2] : r_last[n2];
          r_last[n2] = 0.5f * (base + r_label[(ptt * BB + BB - 1) * NN + n2]);
        }
      }
    }
    __syncthreads();
    for (int b = 0; b < BB; b++) {
      int tn = tar[ptt * BB + b];                  // block-uniform
      if ((tn >> 6) != (int)blockIdx.x) continue;  // uniform branch
      float lg = merge_logit(part + b * NBLK * PSTRIDE, wvo, c0p[0], mred, mfac, tid);
      if (tid == 0) {
        out[ptt * BB + b] = lg;
        r_last[tn] = 0.5f * (lg + r_label[(ptt * BB + BB - 1) * NN + tn]);  // ascending b = last wins
      }
      __syncthreads();
    }
    __syncthreads();
  }

  if (tid < 64) {
    int nc = min(nbase + tid, NN - 1);
    tb_lds[tid] = t_in[(tt * BB + BB - 1) * NN + nc];
    rn_lds[tid] = (tt == 0) ? raw[(BB - 1) * NN + nc] : r_last[nc];
  }
  __syncthreads();

  {
    int nl = lane;
    int nc = min(nbase + nl, NN - 1);
    float tb = tb_lds[nl];
    int swz = (nl & 7) << 3;
    const float4* mp4 = (const float4*)(memPrev + (size_t)nc * 64);
#pragma unroll
    for (int c = 0; c < 4; c++) {
      int kc = wv * 32 + c * 8;   // wave-uniform
      float vv[8];
      if (kc < 64) {
#pragma unroll
        for (int j = 0; j < 8; j++) vv[j] = __cosf(tb * w_t[kc + j] + b_t[kc + j]);
      } else if (tt == 0) {
#pragma unroll
        for (int j = 0; j < 8; j++) vv[j] = 0.f;
      } else {
        int d0 = kc - 64;
        float4 f0 = mp4[d0 >> 2];
        float4 f1 = mp4[(d0 >> 2) + 1];
        vv[0] = f0.x; vv[1] = f0.y; vv[2] = f0.z; vv[3] = f0.w;
        vv[4] = f1.x; vv[5] = f1.y; vv[6] = f1.z; vv[7] = f1.w;
      }
      s16x8 h8, l8;
#pragma unroll
      for (int j = 0; j < 8; j++) {
        unsigned short hb = bf16_rne(vv[j]);
        h8[j] = (short)hb;
        l8[j] = (short)bf16_rne(vv[j] - bf16_to_f(hb));
      }
      int off = nl * 136 + (kc ^ swz);
      *(s16x8*)(XhiS + off) = h8;
      *(s16x8*)(XloS + off) = l8;
    }
  }
  __syncthreads();

  const s16x8* BF8 = (const s16x8*)BF;
  f32x4 acc[4][4];
#pragma unroll
  for (int g = 0; g < 4; g++)
#pragma unroll
    for (int m = 0; m < 4; m++) acc[g][m] = (f32x4){0.f, 0.f, 0.f, 0.f};

  int swzA = (lane & 7) << 3;
#pragma unroll
  for (int kt = 0; kt < 4; kt++) {
    s16x8 bh[4], bl[4];
#pragma unroll
    for (int g = 0; g < 4; g++) {
      int ct = wv + 4 * g;
      bh[g] = BF8[(ct * 4 + kt) * 64 + lane];
      bl[g] = BF8[4096 + (ct * 4 + kt) * 64 + lane];
    }
#pragma unroll
    for (int m = 0; m < 4; m++) {
      int row = 16 * m + (lane & 15);
      int off = row * 136 + ((32 * kt + 8 * (lane >> 4)) ^ swzA);
      s16x8 ah = *(const s16x8*)(XhiS + off);
      s16x8 al = *(const s16x8*)(XloS + off);
#pragma unroll
      for (int g = 0; g < 4; g++) {
        acc[g][m] = __builtin_amdgcn_mfma_f32_16x16x32_bf16(ah, bh[g], acc[g][m], 0, 0, 0);
        acc[g][m] = __builtin_amdgcn_mfma_f32_16x16x32_bf16(ah, bl[g], acc[g][m], 0, 0, 0);
        acc[g][m] = __builtin_amdgcn_mfma_f32_16x16x32_bf16(al, bh[g], acc[g][m], 0, 0, 0);
      }
    }
  }

  int myl = 16 * wv + (lane & 15);
  float4 iv = ((const float4*)i4p)[myl];
  float4 rv = ((const float4*)r4p)[myl];
  int kmem = 64 + myl;
  int slot = kmem & ~7;
  int wel = kmem & 7;
#pragma unroll
  for (int m = 0; m < 4; m++) {
#pragma unroll
    for (int i = 0; i < 4; i++) {
      int nloc = 16 * m + (lane >> 4) * 4 + i;
      float rn = rn_lds[nloc];
      float gRv = acc[0][m][i] + iv.x + rn * rv.x;
      float gZv = acc[1][m][i] + iv.y + rn * rv.y;
      float aNv = acc[2][m][i] + iv.z + rn * rv.z;
      float hNv = acc[3][m][i] + iv.w;
      float rg = sigm(gRv);
      float zg = sigm(gZv);
      float ng = tanh_fast(aNv + rg * hNv);
      int offm = nloc * 136 + (slot ^ ((nloc & 7) << 3)) + wel;
      float mp = bf16_to_f(XhiS[offm]) + bf16_to_f(XloS[offm]);
      int n = nbase + nloc;
      if (n < NN) memNext[(size_t)n * 64 + myl] = (1.f - zg) * ng + zg * mp;
    }
  }

  // ---- fused wq tail: block owning tar_b's row computes wqc[b] ----
  for (int b = 0; b < BB; b++) {
    int tn = tar[tt * BB + b];                  // block-uniform
    if ((tn >> 6) != (int)blockIdx.x) continue; // uniform branch
    __syncthreads();                            // memNext row fully written & visible
    if (tid < 64) q_lds[tid] = memNext[(size_t)tn * 64 + tid];
    __syncthreads();
    float tr = (tt == 0) ? raw[b * NN + tn] : r_last[tn];
    if (tid < 129) {
      const float* Ar = A + tid * 65;
      float acc2 = wq0[tid] + tr * Ar[0];
#pragma unroll 8
      for (int k = 0; k < 64; k++) acc2 += q_lds[k] * Ar[1 + k];
      wqc[b * 132 + tid] = acc2;
    } else if (tid == 129) {
      float acc2 = c0q[0] + tr * cA[0];
      for (int k = 0; k < 64; k++) acc2 += q_lds[k] * cA[1 + k];
      wqc[b * 132 + 129] = acc2;
    }
    __syncthreads();
  }
}

// ---------------- attention: wqc preloaded; 4-way phase-2 with 8 acc chains ----------
__global__ __launch_bounds__(256) void k_attn(
    const float* __restrict__ t_in, const float* __restrict__ raw,
    const float* __restrict__ r_last, const int* __restrict__ n_mask,
    const float* __restrict__ w_t, const float* __restrict__ b_t,
    const float* __restrict__ wqc, const float* __restrict__ mem2,
    float* __restrict__ part, int tt) {
  __shared__ float wq_lds[132];
  __shared__ float e_sh[256], t_sh[256];
  __shared__ float red4[4], redS[4], redR[4];
  __shared__ float pmw[4][64], pew[4][64];

  int tid = threadIdx.x;
  int lane = tid & 63;
  int wvid = tid >> 6;
  int b = blockIdx.y;
  int n0 = blockIdx.x * 256;
  int n = n0 + tid;
  int nc = min(n, NN - 1);
  bool valid = (n < NN);

  if (tid < 130) wq_lds[tid] = wqc[b * 132 + tid];

  float tb = t_in[(tt * BB + b) * NN + nc];
  int mk = n_mask[(tt * BB + b) * NN + nc];
  float rn = (tt == 0) ? raw[b * NN + nc] : r_last[nc];
  __syncthreads();

  float sc = rn * wq_lds[0];
  const float4* m4 = (const float4*)(mem2 + (size_t)nc * 64);
#pragma unroll
  for (int q = 0; q < 16; q++) {
    float4 v = m4[q];
    sc += v.x * wq_lds[1 + 4 * q] + v.y * wq_lds[2 + 4 * q] +
          v.z * wq_lds[3 + 4 * q] + v.w * wq_lds[4 + 4 * q];
  }
#pragma unroll 8
  for (int l = 0; l < 64; l++) sc += __cosf(tb * w_t[l] + b_t[l]) * wq_lds[65 + l];
  float score = (sc + wq_lds[129]) * 0.125f;
  bool act = valid && (mk > 0);

  float mw = wred_max(act ? score : -1e30f);
  if (lane == 0) red4[wvid] = mw;
  __syncthreads();
  float mb = fmaxf(fmaxf(red4[0], red4[1]), fmaxf(red4[2], red4[3]));

  float e = act ? __expf(score - mb) : 0.f;
  float sw = wred_sum(e);
  float sr = wred_sum(e * rn);
  if (lane == 0) { redS[wvid] = sw; redR[wvid] = sr; }
  e_sh[tid] = e;
  t_sh[tid] = tb;
  __syncthreads();
  float Sb = redS[0] + redS[1] + redS[2] + redS[3];
  float Rb = redR[0] + redR[1] + redR[2] + redR[3];

  {
    int ib = wvid * 64;
    float a0 = 0.f, a1 = 0.f, a2 = 0.f, a3 = 0.f;
    float a4 = 0.f, a5 = 0.f, a6 = 0.f, a7 = 0.f;
#pragma unroll 2
    for (int i = 0; i < 64; i += 8) {
      int i0 = ib + i;
      a0 += e_sh[i0 + 0] * mem2[(size_t)min(n0 + i0 + 0, NN - 1) * 64 + lane];
      a1 += e_sh[i0 + 1] * mem2[(size_t)min(n0 + i0 + 1, NN - 1) * 64 + lane];
      a2 += e_sh[i0 + 2] * mem2[(size_t)min(n0 + i0 + 2, NN - 1) * 64 + lane];
      a3 += e_sh[i0 + 3] * mem2[(size_t)min(n0 + i0 + 3, NN - 1) * 64 + lane];
      a4 += e_sh[i0 + 4] * mem2[(size_t)min(n0 + i0 + 4, NN - 1) * 64 + lane];
      a5 += e_sh[i0 + 5] * mem2[(size_t)min(n0 + i0 + 5, NN - 1) * 64 + lane];
      a6 += e_sh[i0 + 6] * mem2[(size_t)min(n0 + i0 + 6, NN - 1) * 64 + lane];
      a7 += e_sh[i0 + 7] * mem2[(size_t)min(n0 + i0 + 7, NN - 1) * 64 + lane];
    }
    pmw[wvid][lane] = ((a0 + a1) + (a2 + a3)) + ((a4 + a5) + (a6 + a7));
    float wl = w_t[lane], bl = b_t[lane];
    float peA = 0.f;
#pragma unroll 4
    for (int i = 0; i < 64; i++) peA += e_sh[ib + i] * __cosf(t_sh[ib + i] * wl + bl);
    pew[wvid][lane] = peA;
  }
  __syncthreads();

  int pbase = (b * NBLK + blockIdx.x) * PSTRIDE;
  if (tid < 64) part[pbase + 1 + tid] = (pmw[0][tid] + pmw[1][tid]) + (pmw[2][tid] + pmw[3][tid]);
  else if (tid < 128) {
    int d = tid - 64;
    part[pbase + 65 + d] = (pew[0][d] + pew[1][d]) + (pew[2][d] + pew[3][d]);
  }
  else if (tid == 128) part[pbase + 0] = Rb;
  else if (tid == 129) part[pbase + 129] = mb;
  else if (tid == 130) part[pbase + 130] = Sb;
}

// ---------------- final logits for the last step (8 blocks) ----------------
__global__ __launch_bounds__(256) void k_fin(
    const float* __restrict__ part, const float* __restrict__ wvo,
    const float* __restrict__ c0p, float* __restrict__ out, int tt) {
  __shared__ float red[256], fac[NBLK];
  int tid = threadIdx.x;
  int b = blockIdx.x;
  float lg = merge_logit(part + b * NBLK * PSTRIDE, wvo, c0p[0], red, fac, tid);
  if (tid == 0) out[tt * BB + b] = lg;
}

extern "C" void kernel_launch(void* const* d_in, const int* in_sizes, int n_in,
                              void* d_out, int out_size, void* d_ws, size_t ws_size,
                              hipStream_t stream) {
  const float* raw     = (const float*)d_in[0];
  const float* r_label = (const float*)d_in[1];
  const float* t_in    = (const float*)d_in[2];
  const int*   tar     = (const int*)d_in[4];
  const int*   n_mask  = (const int*)d_in[5];
  const float* w_t     = (const float*)d_in[6];
  const float* b_t     = (const float*)d_in[7];
  const float* W_msg   = (const float*)d_in[8];
  const float* b_msg   = (const float*)d_in[9];
  const float* Wi      = (const float*)d_in[10];
  const float* Wh      = (const float*)d_in[11];
  const float* bi      = (const float*)d_in[12];
  const float* bh      = (const float*)d_in[13];
  const float* Wq      = (const float*)d_in[14];
  const float* bq      = (const float*)d_in[15];
  const float* Wk      = (const float*)d_in[16];
  const float* bk      = (const float*)d_in[17];
  const float* Wv      = (const float*)d_in[18];
  const float* bv      = (const float*)d_in[19];
  const float* W_out   = (const float*)d_in[20];
  const float* b_out   = (const float*)d_in[21];

  float* ws  = (float*)d_ws;
  float* out = (float*)d_out;

  k_setup<<<34, 1024, 0, stream>>>(W_msg, Wi, bi, b_msg, bh, Wh, Wq, bq, Wk, bk,
                                   Wv, bv, W_out, b_out, b_t, ws);
  k_pack<<<32, 1024, 0, stream>>>(ws, ws);

  for (int tt = 0; tt < TSTEPS; tt++) {
    float* mp = ws + ((tt & 1) ? OFF_MEMB : OFF_MEMA);
    float* mn = ws + ((tt & 1) ? OFF_MEMA : OFF_MEMB);
    k_gru<<<dim3((NN + 63) / 64), dim3(256), 0, stream>>>(
        t_in, raw, ws + OFF_RLAST, w_t, b_t,
        ws + OFF_I4, ws + OFF_R4, (const unsigned short*)(ws + OFF_BFRAG),
        mp, mn, tar, ws + OFF_A, ws + OFF_WQ0, ws + OFF_CA, ws + OFF_C0Q,
        ws + OFF_WQC, ws + OFF_PART, ws + OFF_WVO, ws + OFF_C0,
        r_label, out, tt);
    k_attn<<<dim3(NBLK, BB), dim3(256), 0, stream>>>(
        t_in, raw, ws + OFF_RLAST, n_mask, w_t, b_t,
        ws + OFF_WQC, mn, ws + OFF_PART, tt);
  }
  k_fin<<<dim3(BB), dim3(256), 0, stream>>>(
      ws + OFF_PART, ws + OFF_WVO, ws + OFF_C0, out, TSTEPS - 1);
}